// Round 4
// baseline (314.007 us; speedup 1.0000x reference)
//
#include <hip/hip_runtime.h>

// Problem constants
constexpr int B    = 32;
constexpr int N    = 1568;
constexpr int N0   = 3136;
constexpr int Nt   = 784;
constexpr int Cin  = 256;
constexpr int Cout = 512;
constexpr int H    = 56;
constexpr int W    = 56;
constexpr int HW   = 3136;
constexpr int Ho   = 28;
constexpr int Wo   = 28;
constexpr int HWo  = 784;
constexpr int RR   = B * Nt;      // 25088 GEMM rows
constexpr int NE   = B * N0;      // 100352 entries per index list
constexpr int NBP  = B * HW;      // 100352 pixel bins
constexpr int NBT  = B * Nt;      // 25088 token bins
constexpr int NB   = NBP + NBT;   // 125440 bins
constexpr int NCHUNK = NB / 256;  // 490
constexpr size_t XTOT = (size_t)B * N * Cin;   // 12,845,056 x elements

// Workspace layout (4-byte words). hist + BN stats contiguous -> one memset.
constexpr size_t W_HIST  = 0;                         // NB ints (zeroed)
constexpr size_t W_S1SUM = NB;                        // 256
constexpr size_t W_S1SQ  = W_S1SUM + Cin;             // 256
constexpr size_t W_S2SUM = W_S1SQ + Cin;              // 512
constexpr size_t W_S2SQ  = W_S2SUM + Cout;            // 512 (memset region ends)
constexpr size_t W_OFF   = NB + 1536;                 // NB+1 ints (+pad)
constexpr size_t W_CUR   = W_OFF + NB + 8;            // NB ints
constexpr size_t W_P56   = W_CUR + NB;                // NE ints
constexpr size_t W_P28   = W_P56 + NE;                // NE ints
constexpr size_t W_BSUM  = W_P28 + NE;                // 512 ints
constexpr size_t W_SRTS  = W_BSUM + 512;              // NE ints
constexpr size_t W_STS   = W_SRTS + NE;               // NE ints
constexpr size_t W_STP   = W_STS + NE;                // NE ints
constexpr size_t W_STW   = W_STP + NE;                // NE floats
constexpr size_t W_CONVB = W_STW + NE;                // B*HWo*Cin bf16 -> /2 words
constexpr size_t W_YBF   = W_CONVB + (size_t)B * HWo * Cin / 2;  // RR*Cin bf16
constexpr size_t W_WFB   = W_YBF + (size_t)RR * Cin / 2;         // Cout*Cin bf16
constexpr size_t W_BIAS  = W_WFB + (size_t)Cout * Cin / 2;       // 512
constexpr size_t W_A2    = W_BIAS + Cout;             // 512
constexpr size_t W_C2    = W_A2 + Cout;               // 512
constexpr size_t W_ZB    = W_C2 + Cout;               // RR*Cout bf16 -> /2 words
constexpr size_t W_XH    = W_ZB + (size_t)RR * Cout / 2;  // XTOT bf16 -> /2 words

__device__ __forceinline__ int pix_of(float t, float scale) {
    t = fminf(fmaxf(t, -1.0f), 1.0f);
    float u = __fadd_rn(__fmul_rn(t, 0.5f), 0.5f);   // no fma contraction
    return (int)rintf(__fmul_rn(u, scale));          // round-half-even == jnp.round
}
__device__ __forceinline__ unsigned short f2bf(float f) {
    unsigned int u = __float_as_uint(f);
    u = (u + 0x7fffu + ((u >> 16) & 1u)) >> 16;      // RNE
    return (unsigned short)u;
}
__device__ __forceinline__ float bf2f(unsigned short h) {
    return __uint_as_float(((unsigned int)h) << 16);
}

// ---- cast x to bf16 (halves hot set: 1.6 -> 0.8 MB per batch slice) ---------
__global__ void k_cast(const float* __restrict__ x, uint2* __restrict__ xh2) {
    size_t i = (size_t)blockIdx.x * 256 + threadIdx.x;   // 4 floats per thread
    float4 v = *(const float4*)&x[i * 4];
    uint2 o;
    o.x = (unsigned int)f2bf(v.x) | ((unsigned int)f2bf(v.y) << 16);
    o.y = (unsigned int)f2bf(v.z) | ((unsigned int)f2bf(v.w) << 16);
    xh2[i] = o;
}

// ---- sort phase -------------------------------------------------------------
__global__ void k_hist(const float* __restrict__ loc, const int* __restrict__ idxt,
                       int* __restrict__ hist, int* __restrict__ p56a, int* __restrict__ p28a) {
    int i = blockIdx.x * 256 + threadIdx.x;
    if (i >= NE) return;
    int b = i / N0;
    float lx = loc[(size_t)2 * i], ly = loc[(size_t)2 * i + 1];
    int p56 = pix_of(ly, 55.0f) * W + pix_of(lx, 55.0f);
    int p28 = pix_of(ly, 27.0f) * Wo + pix_of(lx, 27.0f);
    p56a[i] = p56; p28a[i] = p28;
    atomicAdd(&hist[b * HW + p56], 1);
    atomicAdd(&hist[NBP + b * Nt + idxt[i]], 1);
}

__global__ void k_scanA(const int* __restrict__ hist, int* __restrict__ bsum) {
    __shared__ int sm[256];
    int i = blockIdx.x * 256 + threadIdx.x;
    sm[threadIdx.x] = hist[i];
    __syncthreads();
    for (int d = 128; d > 0; d >>= 1) {
        if (threadIdx.x < d) sm[threadIdx.x] += sm[threadIdx.x + d];
        __syncthreads();
    }
    if (threadIdx.x == 0) bsum[blockIdx.x] = sm[0];
}

__global__ void k_scanB(int* __restrict__ bsum) {
    __shared__ int sm[512];
    int t = threadIdx.x;
    int v = (t < NCHUNK) ? bsum[t] : 0;
    sm[t] = v; __syncthreads();
    for (int d = 1; d < 512; d <<= 1) {
        int u = (t >= d) ? sm[t - d] : 0;
        __syncthreads();
        sm[t] += u;
        __syncthreads();
    }
    if (t < NCHUNK) bsum[t] = sm[t] - v;
}

__global__ void k_scanC(const int* __restrict__ hist, const int* __restrict__ bsum,
                        int* __restrict__ off, int* __restrict__ cur) {
    __shared__ int sm[256];
    int t = threadIdx.x;
    int i = blockIdx.x * 256 + t;
    int v = hist[i];
    sm[t] = v; __syncthreads();
    for (int d = 1; d < 256; d <<= 1) {
        int u = (t >= d) ? sm[t - d] : 0;
        __syncthreads();
        sm[t] += u;
        __syncthreads();
    }
    int excl = bsum[blockIdx.x] + sm[t] - v;
    off[i] = excl; cur[i] = excl;
    if (i == NB - 1) off[NB] = excl + v;
}

__global__ void k_scatteridx(const int* __restrict__ p56a, const int* __restrict__ p28a,
                             const int* __restrict__ idxa, const int* __restrict__ idxt,
                             const float* __restrict__ wt, int* __restrict__ cur,
                             int* __restrict__ srtS, int* __restrict__ sTs,
                             int* __restrict__ sTp, float* __restrict__ sTw) {
    int i = blockIdx.x * 256 + threadIdx.x;
    if (i >= NE) return;
    int b = i / N0;
    int s = idxa[i];
    int posP = atomicAdd(&cur[b * HW + p56a[i]], 1);
    srtS[posP] = s;
    int posT = atomicAdd(&cur[NBP + b * Nt + idxt[i]], 1) - NE;
    sTs[posT] = s; sTp[posT] = p28a[i]; sTw[posT] = wt[i];
}

// ---- fused token2map + 3x3 dw s2 conv; bf16 x, 4 loads in flight ------------
constexpr int GCAP = 512;
__global__ __launch_bounds__(256) void k_gconv(const unsigned short* __restrict__ xh,
        const int* __restrict__ off, const int* __restrict__ srtS,
        const float* __restrict__ dww, unsigned short* __restrict__ convb) {
    __shared__ int   sPk[GCAP];
    __shared__ float sRc[GCAP];
    __shared__ float sWv[9 * 256];    // [tap][c] conv weights (avoid dyn reg index)
    __shared__ int sSt[9], sCt[9], sPref[10];
    int blk = blockIdx.x;            // b*HWo + oy*Wo + ox
    int c   = threadIdx.x;
    int b   = blk / HWo;
    int rem = blk - b * HWo;
    int oy  = rem / Wo;
    int ox  = rem - oy * Wo;
#pragma unroll
    for (int k = 0; k < 9; ++k) sWv[k * 256 + c] = dww[c * 9 + k];
    if (c < 9) {                     // all 9 bin ranges in parallel
        int ky = c / 3, kx = c - ky * 3;
        int iy = oy * 2 - 1 + ky, ix = ox * 2 - 1 + kx;
        int st = 0, ct = 0;
        if (iy >= 0 && iy < H && ix >= 0 && ix < W) {
            int bin = b * HW + iy * W + ix;
            st = off[bin];
            ct = off[bin + 1] - st;
        }
        sSt[c] = st; sCt[c] = ct;
    }
    __syncthreads();
    if (c == 0) {
        int a = 0;
#pragma unroll
        for (int k = 0; k < 9; ++k) { sPref[k] = a; a += sCt[k]; }
        sPref[9] = a;
    }
    __syncthreads();
    int T = sPref[9];
    const unsigned short* xb = xh + (size_t)b * N * Cin + c;
    float a0 = 0.0f, a1 = 0.0f, a2 = 0.0f, a3 = 0.0f;
    for (int base = 0; base < T; base += GCAP) {
        if (c < 9) {                 // fill contributor list (tap-packed)
            int ct = sCt[c], pr = sPref[c], st = sSt[c];
            float rc = 1.0f / ((float)ct + 1e-6f);
            int j0 = max(base - pr, 0);
            int j1 = min(base + GCAP - pr, ct);
            for (int j = j0; j < j1; ++j) {
                sPk[pr + j - base] = srtS[st + j] | (c << 16);
                sRc[pr + j - base] = rc;
            }
        }
        __syncthreads();
        int cnt = min(T - base, GCAP);
        int j = 0;
        for (; j + 4 <= cnt; j += 4) {   // 4 independent load chains
            int pk0 = sPk[j], pk1 = sPk[j + 1], pk2 = sPk[j + 2], pk3 = sPk[j + 3];
            float r0 = sRc[j], r1 = sRc[j + 1], r2 = sRc[j + 2], r3 = sRc[j + 3];
            float x0 = bf2f(xb[(size_t)(pk0 & 0xFFFF) * Cin]);
            float x1 = bf2f(xb[(size_t)(pk1 & 0xFFFF) * Cin]);
            float x2 = bf2f(xb[(size_t)(pk2 & 0xFFFF) * Cin]);
            float x3 = bf2f(xb[(size_t)(pk3 & 0xFFFF) * Cin]);
            a0 = fmaf(x0 * r0, sWv[(pk0 >> 16) * 256 + c], a0);
            a1 = fmaf(x1 * r1, sWv[(pk1 >> 16) * 256 + c], a1);
            a2 = fmaf(x2 * r2, sWv[(pk2 >> 16) * 256 + c], a2);
            a3 = fmaf(x3 * r3, sWv[(pk3 >> 16) * 256 + c], a3);
        }
        for (; j < cnt; ++j) {
            int pk = sPk[j];
            a0 = fmaf(bf2f(xb[(size_t)(pk & 0xFFFF) * Cin]) * sRc[j],
                      sWv[(pk >> 16) * 256 + c], a0);
        }
        __syncthreads();
    }
    convb[(size_t)blk * Cin + c] = f2bf((a0 + a1) + (a2 + a3));
}

// ---- fused map2token + skip; bf16 sources, 4 loads in flight ----------------
constexpr int TCAP = 256;
__global__ __launch_bounds__(256) void k_gtok(const unsigned short* __restrict__ xh,
        const unsigned short* __restrict__ convb, const int* __restrict__ off,
        const int* __restrict__ sTs, const int* __restrict__ sTp,
        const float* __restrict__ sTw, const float* __restrict__ skipw,
        unsigned short* __restrict__ ybf) {
    __shared__ int sS[TCAP];
    __shared__ int sP[TCAP];
    __shared__ float sW[TCAP];
    int bt = blockIdx.x;
    int c  = threadIdx.x;
    int b  = bt / Nt;
    int st = off[NBP + bt] - NE, en = off[NBP + bt + 1] - NE;
    int T = en - st;
    float sk = skipw[c];
    const unsigned short* xb = xh + (size_t)b * N * Cin + c;
    const unsigned short* cb = convb + (size_t)b * HWo * Cin + c;
    float acc0 = 0.0f, acc1 = 0.0f, wsum = 0.0f;
    for (int base = 0; base < T; base += TCAP) {
        int cnt = min(T - base, TCAP);
        if (c < cnt) {
            sS[c] = sTs[st + base + c];
            sP[c] = sTp[st + base + c];
            sW[c] = sTw[st + base + c];
        }
        __syncthreads();
        int j = 0;
        for (; j + 2 <= cnt; j += 2) {    // 4 independent loads (2 pairs)
            int s0 = sS[j], p0 = sP[j], s1 = sS[j + 1], p1 = sP[j + 1];
            float w0 = sW[j], w1 = sW[j + 1];
            float cv0 = bf2f(cb[(size_t)p0 * Cin]);
            float xv0 = bf2f(xb[(size_t)s0 * Cin]);
            float cv1 = bf2f(cb[(size_t)p1 * Cin]);
            float xv1 = bf2f(xb[(size_t)s1 * Cin]);
            wsum += w0 + w1;
            acc0 = fmaf(w0, fmaf(sk, xv0, cv0), acc0);
            acc1 = fmaf(w1, fmaf(sk, xv1, cv1), acc1);
        }
        if (j < cnt) {
            int s0 = sS[j], p0 = sP[j];
            float w0 = sW[j];
            wsum += w0;
            acc0 = fmaf(w0, fmaf(sk, bf2f(xb[(size_t)s0 * Cin]), bf2f(cb[(size_t)p0 * Cin])), acc0);
        }
        __syncthreads();
    }
    ybf[(size_t)bt * Cin + c] = f2bf((acc0 + acc1) * (1.0f / (wsum + 1e-6f)));
}

// ---- BN1 stats over bf16 y --------------------------------------------------
__global__ void k_ystats(const unsigned short* __restrict__ ybf,
                         float* __restrict__ s1, float* __restrict__ s1q) {
    int c = threadIdx.x;
    float sum = 0.0f, sq = 0.0f;
    for (int r = blockIdx.x; r < RR; r += gridDim.x) {
        float v = bf2f(ybf[(size_t)r * Cin + c]);
        sum += v;
        sq = fmaf(v, v, sq);
    }
    atomicAdd(&s1[c], sum);
    atomicAdd(&s1q[c], sq);
}

// ---- fold BN1 into bf16 weight [Cout][Cin] + fp32 bias ----------------------
__global__ void k_fold(const float* __restrict__ s1, const float* __restrict__ s1q,
                       const float* __restrict__ g1, const float* __restrict__ b1,
                       const float* __restrict__ convw, unsigned short* __restrict__ wfb,
                       float* __restrict__ bias) {
    int o = blockIdx.x, c = threadIdx.x;
    const float inv = 1.0f / (float)RR;
    float mu  = s1[c] * inv;
    float var = s1q[c] * inv - mu * mu;
    float a   = g1[c] / sqrtf(var + 1e-5f);
    float bs  = b1[c] - mu * a;
    float wv  = convw[(size_t)o * Cin + c];
    wfb[(size_t)o * Cin + c] = f2bf(wv * a);
    __shared__ float red[256];
    red[c] = wv * bs;
    __syncthreads();
    for (int st = 128; st > 0; st >>= 1) {
        if (c < st) red[c] += red[c + st];
        __syncthreads();
    }
    if (c == 0) bias[o] = red[0];
}

// ---- bf16 MFMA GEMM with fused BN2 stats; bf16 z out ------------------------
typedef __attribute__((ext_vector_type(8))) short short8;
typedef __attribute__((ext_vector_type(4))) float f32x4;

__global__ __launch_bounds__(256) void k_gemm(const unsigned short* __restrict__ A,
        const unsigned short* __restrict__ Bt, const float* __restrict__ bias,
        unsigned short* __restrict__ zb, float* __restrict__ s2, float* __restrict__ s2q) {
    constexpr int BK = 32, LS = 48;
    __shared__ unsigned short As[128 * LS];
    __shared__ unsigned short Bs[128 * LS];
    __shared__ float rsum[128], rsq[128];
    int m0 = blockIdx.x * 128, n0 = blockIdx.y * 128;
    int t = threadIdx.x;
    int wave = t >> 6, lane = t & 63;
    int wm = wave >> 1, wn = wave & 1;
    int l16 = lane & 15, lq = lane >> 4;
    f32x4 acc[4][4];
#pragma unroll
    for (int i = 0; i < 4; ++i)
#pragma unroll
        for (int j = 0; j < 4; ++j) acc[i][j] = (f32x4)0.0f;
    if (t < 128) { rsum[t] = 0.0f; rsq[t] = 0.0f; }

    for (int k0 = 0; k0 < Cin; k0 += BK) {
#pragma unroll
        for (int r2 = 0; r2 < 2; ++r2) {
            int e = r2 * 256 + t;
            int row = e >> 2, kc = (e & 3) * 8;
            *(float4*)&As[row * LS + kc] = *(const float4*)&A[((size_t)(m0 + row)) * Cin + k0 + kc];
            *(float4*)&Bs[row * LS + kc] = *(const float4*)&Bt[((size_t)(n0 + row)) * Cin + k0 + kc];
        }
        __syncthreads();
        short8 af[4], bf[4];
#pragma unroll
        for (int i = 0; i < 4; ++i) {
            af[i] = *(short8*)&As[(wm * 64 + i * 16 + l16) * LS + lq * 8];
            bf[i] = *(short8*)&Bs[(wn * 64 + i * 16 + l16) * LS + lq * 8];
        }
#pragma unroll
        for (int i = 0; i < 4; ++i)
#pragma unroll
            for (int j = 0; j < 4; ++j)
                acc[i][j] = __builtin_amdgcn_mfma_f32_16x16x32_bf16(af[i], bf[j], acc[i][j], 0, 0, 0);
        __syncthreads();
    }
#pragma unroll
    for (int j = 0; j < 4; ++j) {
        int cl  = wn * 64 + j * 16 + l16;
        int col = n0 + cl;
        float bv = bias[col];
        float ps = 0.0f, pq = 0.0f;
#pragma unroll
        for (int i = 0; i < 4; ++i) {
            int rbase = m0 + wm * 64 + i * 16 + lq * 4;
#pragma unroll
            for (int r = 0; r < 4; ++r) {
                float v = acc[i][j][r] + bv;
                zb[(size_t)(rbase + r) * Cout + col] = f2bf(v);
                ps += v;
                pq = fmaf(v, v, pq);
            }
        }
        atomicAdd(&rsum[cl], ps);
        atomicAdd(&rsq[cl], pq);
    }
    __syncthreads();
    if (t < 128) {
        atomicAdd(&s2[n0 + t], rsum[t]);
        atomicAdd(&s2q[n0 + t], rsq[t]);
    }
}

// ---- BN2 fold ---------------------------------------------------------------
__global__ void k_fold2(const float* __restrict__ s2, const float* __restrict__ s2q,
                        const float* __restrict__ g2, const float* __restrict__ b2,
                        float* __restrict__ a2, float* __restrict__ c2) {
    int o = threadIdx.x;
    const float inv = 1.0f / (float)RR;
    float mu  = s2[o] * inv;
    float var = s2q[o] * inv - mu * mu;
    float a   = g2[o] / sqrtf(var + 1e-5f);
    a2[o] = a;
    c2[o] = b2[o] - mu * a;
}

// ---- BN2 normalize + ReLU: bf16 z -> fp32 out -------------------------------
__global__ void k_final(const unsigned short* __restrict__ zb, const float* __restrict__ a2,
                        const float* __restrict__ c2, float* __restrict__ out) {
    size_t j4 = ((size_t)blockIdx.x * 256 + threadIdx.x) * 4;
    int o = (int)(j4 & (Cout - 1));
    uint2 u = *(const uint2*)&zb[j4];
    float e0 = bf2f((unsigned short)(u.x & 0xffffu));
    float e1 = bf2f((unsigned short)(u.x >> 16));
    float e2 = bf2f((unsigned short)(u.y & 0xffffu));
    float e3 = bf2f((unsigned short)(u.y >> 16));
    float4 r;
    r.x = fmaxf(fmaf(e0, a2[o + 0], c2[o + 0]), 0.0f);
    r.y = fmaxf(fmaf(e1, a2[o + 1], c2[o + 1]), 0.0f);
    r.z = fmaxf(fmaf(e2, a2[o + 2], c2[o + 2]), 0.0f);
    r.w = fmaxf(fmaf(e3, a2[o + 3], c2[o + 3]), 0.0f);
    *(float4*)&out[j4] = r;
}

extern "C" void kernel_launch(void* const* d_in, const int* in_sizes, int n_in,
                              void* d_out, int out_size, void* d_ws, size_t ws_size,
                              hipStream_t stream) {
    const float* x     = (const float*)d_in[0];
    const float* loc   = (const float*)d_in[1];
    const int*   idxa  = (const int*)d_in[2];
    const int*   idxt  = (const int*)d_in[4];
    const float* wt    = (const float*)d_in[5];
    const float* dww   = (const float*)d_in[9];
    const float* skipw = (const float*)d_in[10];
    const float* convw = (const float*)d_in[11];
    const float* g1    = (const float*)d_in[12];
    const float* b1    = (const float*)d_in[13];
    const float* g2    = (const float*)d_in[14];
    const float* b2    = (const float*)d_in[15];

    float* ws = (float*)d_ws;
    int*   hist  = (int*)(ws + W_HIST);
    float* s1sum = ws + W_S1SUM;
    float* s1sq  = ws + W_S1SQ;
    float* s2sum = ws + W_S2SUM;
    float* s2sq  = ws + W_S2SQ;
    int*   off   = (int*)(ws + W_OFF);
    int*   cur   = (int*)(ws + W_CUR);
    int*   p56a  = (int*)(ws + W_P56);
    int*   p28a  = (int*)(ws + W_P28);
    int*   bsum  = (int*)(ws + W_BSUM);
    int*   srtS  = (int*)(ws + W_SRTS);
    int*   sTs   = (int*)(ws + W_STS);
    int*   sTp   = (int*)(ws + W_STP);
    float* sTw   = ws + W_STW;
    unsigned short* convb = (unsigned short*)(ws + W_CONVB);
    unsigned short* ybf   = (unsigned short*)(ws + W_YBF);
    unsigned short* wfb   = (unsigned short*)(ws + W_WFB);
    float* bias  = ws + W_BIAS;
    float* a2    = ws + W_A2;
    float* c2    = ws + W_C2;
    unsigned short* zb = (unsigned short*)(ws + W_ZB);
    unsigned short* xh = (unsigned short*)(ws + W_XH);
    float* out   = (float*)d_out;

    hipMemsetAsync(hist, 0, (size_t)(NB + 1536) * sizeof(float), stream);

    k_cast<<<(int)(XTOT / 4 / 256), 256, 0, stream>>>(x, (uint2*)xh);
    k_hist<<<NE / 256, 256, 0, stream>>>(loc, idxt, hist, p56a, p28a);
    k_scanA<<<NCHUNK, 256, 0, stream>>>(hist, bsum);
    k_scanB<<<1, 512, 0, stream>>>(bsum);
    k_scanC<<<NCHUNK, 256, 0, stream>>>(hist, bsum, off, cur);
    k_scatteridx<<<NE / 256, 256, 0, stream>>>(p56a, p28a, idxa, idxt, wt, cur, srtS, sTs, sTp, sTw);

    k_gconv<<<B * HWo, 256, 0, stream>>>(xh, off, srtS, dww, convb);
    k_gtok<<<NBT, 256, 0, stream>>>(xh, convb, off, sTs, sTp, sTw, skipw, ybf);
    k_ystats<<<256, 256, 0, stream>>>(ybf, s1sum, s1sq);
    k_fold<<<Cout, 256, 0, stream>>>(s1sum, s1sq, g1, b1, convw, wfb, bias);

    dim3 gg(RR / 128, Cout / 128);
    k_gemm<<<gg, 256, 0, stream>>>(ybf, wfb, bias, zb, s2sum, s2sq);
    k_fold2<<<1, 512, 0, stream>>>(s2sum, s2sq, g2, b2, a2, c2);
    k_final<<<(int)(((size_t)RR * Cout) / 1024), 256, 0, stream>>>(zb, a2, c2, out);
}